// Round 10
// baseline (516.020 us; speedup 1.0000x reference)
//
#include <hip/hip_runtime.h>

// Problem constants (fixed by reference)
#define N_SRC   100000
#define N_DSTC  50000
#define N_EDGES 1000000
#define DIM     64
#define NCLS    64

// K-tiling of the gather: 16 src octiles -> per-phase x working set 1.6 MB
#define NOCT    16
#define OCT_DIV 6250                       // N_SRC / NOCT
#define NKEYS   (N_DSTC * NOCT)            // 800000

#define SCAN_BPB 1024
#define SCAN_NB  ((NKEYS + SCAN_BPB - 1) / SCAN_BPB)   // 782

#define HIST_BLOCKS ((N_EDGES / 4 + 255) / 256)        // 977
#define REG_BLOCKS  1024
#define GATHER_GRID 1024                   // 4 blocks/CU -> all co-resident
#define TOT_WAVES   (GATHER_GRID * 4)      // 4096
#define ROWS_PW     13                     // ceil(N_DSTC / TOT_WAVES)

// ws layout (4-byte slots) -- hist overlays sorted_src (hist dead before
// reorder writes sorted_src):
//   sorted_src [0, 1000000)        int   (hist = [0, 800000) early)
//   colsum     [1000000, +64)      float (zeroed)
//   regA       [1000064]           float (zeroed)
//   regB       [1000065, +64)      float (zeroed)
//   doneG      [1000129]           int   (zeroed)
//   blockSums  [1000130, +782)     int   (fully written by scan_local)
//   cursor     [1000912, +800000)  int   (fully written by scan chain)

// ---------------------------------------------------------------------------
// K1: fused key-histogram (blocks [0,HIST_BLOCKS)) and reg A/B accumulation
// (blocks [HIST_BLOCKS, HIST_BLOCKS+REG_BLOCKS)). Disjoint independent work.
__global__ __launch_bounds__(256) void hist_reg_kernel(
    const int4*  __restrict__ src4,
    const int4*  __restrict__ dst4,
    const float* __restrict__ x,
    const float* __restrict__ u_sum,
    int*   __restrict__ hist,
    float* __restrict__ regA,
    float* __restrict__ regB) {
  __shared__ float redB[4][64];
  __shared__ float redA[4];

  if (blockIdx.x < HIST_BLOCKS) {
    int i = blockIdx.x * blockDim.x + threadIdx.x;
    if (i < N_EDGES / 4) {
      int4 s = src4[i];
      int4 d = dst4[i];
      atomicAdd(&hist[d.x * NOCT + s.x / OCT_DIV], 1);
      atomicAdd(&hist[d.y * NOCT + s.y / OCT_DIV], 1);
      atomicAdd(&hist[d.z * NOCT + s.z / OCT_DIV], 1);
      atomicAdd(&hist[d.w * NOCT + s.w / OCT_DIV], 1);
    }
    return;
  }

  // reg part: lane owns column c = lane (pure f32).
  const int tid  = threadIdx.x;
  const int wv   = tid >> 6;
  const int lane = tid & 63;
  const int waveId     = (blockIdx.x - HIST_BLOCKS) * 4 + wv;
  const int totalWaves = REG_BLOCKS * 4;

  float accA = 0.0f;
  float accB = 0.0f;
  for (int r = waveId; r < N_SRC; r += totalWaves) {
    float u  = u_sum[r];                 // wave-uniform -> broadcast
    float xv = x[r * DIM + lane];
    float t  = u * xv;
    accB += t;
    accA = fmaf(t, t, accA);
  }
  #pragma unroll
  for (int off = 32; off > 0; off >>= 1)
    accA += __shfl_down(accA, off, 64);
  if (lane == 0) redA[wv] = accA;
  redB[wv][lane] = accB;
  __syncthreads();
  if (tid < 64) {
    float b = redB[0][tid] + redB[1][tid] + redB[2][tid] + redB[3][tid];
    atomicAdd(&regB[tid], b);
  }
  if (tid == 0) {
    float a = redA[0] + redA[1] + redA[2] + redA[3];
    atomicAdd(regA, a);
  }
}

// ---------------------------------------------------------------------------
// K2a: per-block (1024 keys) exclusive scan; emit block totals.
__global__ __launch_bounds__(1024) void scan_local(
    const int* __restrict__ hist, int* __restrict__ cursor,
    int* __restrict__ blockSums) {
  __shared__ int A[1024], B[1024];
  const int b = blockIdx.x, t = threadIdx.x;
  const int g = b * SCAN_BPB + t;
  int v = (g < NKEYS) ? hist[g] : 0;
  A[t] = v;
  __syncthreads();
  int* cur = A; int* nxt = B;
  for (int off = 1; off < 1024; off <<= 1) {
    int s = cur[t] + ((t >= off) ? cur[t - off] : 0);
    nxt[t] = s;
    __syncthreads();
    int* tmp = cur; cur = nxt; nxt = tmp;
  }
  if (g < NKEYS) cursor[g] = cur[t] - v;   // exclusive within block
  if (t == 1023) blockSums[b] = cur[1023];
}

// K2b: each block redundantly scans the 782 block totals in LDS, then adds
// its own block offset to its 1024 cursor entries.
__global__ __launch_bounds__(1024) void scan_addoff(
    int* __restrict__ cursor, const int* __restrict__ blockSums) {
  __shared__ int A[1024], B[1024];
  const int b = blockIdx.x, t = threadIdx.x;
  A[t] = (t < SCAN_NB) ? blockSums[t] : 0;
  __syncthreads();
  int* cur = A; int* nxt = B;
  for (int off = 1; off < 1024; off <<= 1) {
    int s = cur[t] + ((t >= off) ? cur[t - off] : 0);
    nxt[t] = s;
    __syncthreads();
    int* tmp = cur; cur = nxt; nxt = tmp;
  }
  int off = (b > 0) ? cur[b - 1] : 0;   // exclusive offset of block b
  int g = b * SCAN_BPB + t;
  if (g < NKEYS) cursor[g] += off;
}

// ---------------------------------------------------------------------------
// K3: counting-sort pass 2 on key=(dst*16 + src-octile). After this kernel,
// cursor[k] == end offset of key k.
__global__ __launch_bounds__(256) void reorder_kernel(
    const int4* __restrict__ src4, const int4* __restrict__ dst4,
    int* __restrict__ cursor, int* __restrict__ sorted_src) {
  int i = blockIdx.x * blockDim.x + threadIdx.x;
  if (i < N_EDGES / 4) {
    int4 s = src4[i];
    int4 d = dst4[i];
    int k0 = d.x * NOCT + s.x / OCT_DIV;
    int k1 = d.y * NOCT + s.y / OCT_DIV;
    int k2 = d.z * NOCT + s.z / OCT_DIV;
    int k3 = d.w * NOCT + s.w / OCT_DIV;
    int p0 = atomicAdd(&cursor[k0], 1); sorted_src[p0] = s.x;
    int p1 = atomicAdd(&cursor[k1], 1); sorted_src[p1] = s.y;
    int p2 = atomicAdd(&cursor[k2], 1); sorted_src[p2] = s.z;
    int p3 = atomicAdd(&cursor[k3], 1); sorted_src[p3] = s.w;
  }
}

// ---------------------------------------------------------------------------
// K4: persistent phased gather + mean + GEMV + colsum + last-block combine.
// Grid = 1024 blocks (exactly residency capacity) -> all waves co-resident.
// Each wave owns ROWS_PW dst rows (acc held in registers across phases).
// Phase oc processes only edges with src in octile oc -> per-phase x slice
// = 1.6 MB, forced inside per-XCD L2. Inner machinery = R4-exact
// (es = lane>>4 subgroup, q = lane&15 float4 quadrant, 1-deep).
__global__ __launch_bounds__(256, 4) void gather_h(
    const float* __restrict__ x,
    const float* __restrict__ Ww,   // [64][128]
    const float* __restrict__ Wb,   // [64]
    const int*   __restrict__ cursor,      // end offsets after reorder
    const int*   __restrict__ sorted_src,
    float* __restrict__ h,
    float* __restrict__ colsum,
    float* __restrict__ regA,
    float* __restrict__ regB,
    int*   __restrict__ doneG,
    float* __restrict__ out_scalar) {
  __shared__ float Wt[2 * DIM][NCLS + 1];  // Wt[k][c] = Ww[c*128+k]
  __shared__ float colred[4][64];
  __shared__ int   lastFlag;

  const int tid = threadIdx.x;
  for (int idx = tid; idx < NCLS * 2 * DIM; idx += 256) {
    int c = idx >> 7, k = idx & 127;
    Wt[k][c] = Ww[idx];
  }
  __syncthreads();

  const int wv   = tid >> 6;
  const int lane = tid & 63;
  const int es   = lane >> 4;
  const int q    = lane & 15;
  const int waveId = blockIdx.x * 4 + wv;      // 0..4095
  const float bias = Wb[lane];
  const float4* x4 = reinterpret_cast<const float4*>(x);

  float4 acc[ROWS_PW];
  #pragma unroll
  for (int j = 0; j < ROWS_PW; ++j) acc[j] = make_float4(0.f, 0.f, 0.f, 0.f);

  // ---- phased gather: one src octile at a time ----
  for (int oc = 0; oc < NOCT; ++oc) {
    #pragma unroll
    for (int j = 0; j < ROWS_PW; ++j) {
      int r = waveId + j * TOT_WAVES;
      if (r < N_DSTC) {
        int key = r * NOCT + oc;
        int beg = (key == 0) ? 0 : cursor[key - 1];
        int end = cursor[key];
        int cnt = end - beg;
        for (int base = 0; base < cnt; base += 64) {
          int rem = cnt - base;
          int mm  = rem < 64 ? rem : 64;
          int idxv = (lane < rem) ? sorted_src[beg + base + lane] : 0;
          for (int jb = 0; jb < mm; jb += 4) {
            int jj = jb + es;
            int s0 = __shfl(idxv, jj & 63, 64);
            if (jj < mm) {
              float4 v = x4[s0 * 16 + q];
              acc[j].x += v.x; acc[j].y += v.y;
              acc[j].z += v.z; acc[j].w += v.w;
            }
          }
        }
      }
    }
    __syncthreads();   // keep the block's 4 waves phase-aligned
  }

  // ---- epilogue: reduce, mean, GEMV, store ----
  float4 colacc = make_float4(0.f, 0.f, 0.f, 0.f);
  #pragma unroll
  for (int j = 0; j < ROWS_PW; ++j) {
    int r = waveId + j * TOT_WAVES;
    if (r < N_DSTC) {
      float4 a = acc[j];
      a.x += __shfl_xor(a.x, 16, 64); a.y += __shfl_xor(a.y, 16, 64);
      a.z += __shfl_xor(a.z, 16, 64); a.w += __shfl_xor(a.w, 16, 64);
      a.x += __shfl_xor(a.x, 32, 64); a.y += __shfl_xor(a.y, 32, 64);
      a.z += __shfl_xor(a.z, 32, 64); a.w += __shfl_xor(a.w, 32, 64);

      int begR = (r == 0) ? 0 : cursor[r * NOCT - 1];
      int cnt  = cursor[r * NOCT + (NOCT - 1)] - begR;
      float inv = 1.0f / fmaxf((float)cnt, 1.0f);
      float4 ym = make_float4(a.x * inv, a.y * inv, a.z * inv, a.w * inv);

      float4 xv = x4[r * 16 + q];   // whole wave reads same 256B row

      if (es == 0) {
        colacc.x += ym.x; colacc.y += ym.y;
        colacc.z += ym.z; colacc.w += ym.w;
      }

      float hacc = bias;
      #pragma unroll
      for (int k = 0; k < DIM; ++k) {
        const int sl = k >> 2;  // es==0 lane holding quadrant k>>2
        float fx = __shfl((k & 3) == 0 ? xv.x : (k & 3) == 1 ? xv.y :
                          (k & 3) == 2 ? xv.z : xv.w, sl, 64);
        float fy = __shfl((k & 3) == 0 ? ym.x : (k & 3) == 1 ? ym.y :
                          (k & 3) == 2 ? ym.z : ym.w, sl, 64);
        hacc = fmaf(fx, Wt[k][lane], hacc);
        hacc = fmaf(fy, Wt[DIM + k][lane], hacc);
      }
      h[r * NCLS + lane] = hacc;
    }
  }

  if (es == 0) {  // lane q owns columns 4q..4q+3
    colred[wv][q * 4 + 0] = colacc.x;
    colred[wv][q * 4 + 1] = colacc.y;
    colred[wv][q * 4 + 2] = colacc.z;
    colred[wv][q * 4 + 3] = colacc.w;
  }
  __syncthreads();
  if (tid < 64) {
    float s = colred[0][tid] + colred[1][tid] + colred[2][tid] + colred[3][tid];
    atomicAdd(&colsum[tid], s);
  }

  // ---- last-block reg-loss combine ----
  __syncthreads();
  if (tid == 0) {
    __threadfence();
    int old = atomicAdd(doneG, 1);
    lastFlag = (old == (int)gridDim.x - 1) ? 1 : 0;
  }
  __syncthreads();
  if (lastFlag && tid < 64) {
    const float inv_nd = 1.0f / (float)N_DSTC;
    float cs = atomicAdd(&colsum[tid], 0.0f);   // coherent atomic read
    float bv = atomicAdd(&regB[tid], 0.0f);
    float mx = cs * inv_nd;
    float p = fmaf((float)N_SRC * mx, mx, -2.0f * inv_nd * mx * bv);
    #pragma unroll
    for (int off = 32; off > 0; off >>= 1)
      p += __shfl_down(p, off, 64);
    if (tid == 0) {
      float av = atomicAdd(regA, 0.0f);
      float total = fmaf(av, inv_nd * inv_nd, p);
      out_scalar[0] = total * (1.0f / ((float)N_SRC * (float)NCLS));
    }
  }
}

// ---------------------------------------------------------------------------
extern "C" void kernel_launch(void* const* d_in, const int* in_sizes, int n_in,
                              void* d_out, int out_size, void* d_ws, size_t ws_size,
                              hipStream_t stream) {
  const float* x     = (const float*)d_in[0];
  // d_in[1] = w : dead (only ones_like(w) is used)
  const float* u_sum = (const float*)d_in[2];
  const float* Ww    = (const float*)d_in[3];
  const float* Wb    = (const float*)d_in[4];
  const int*   src   = (const int*)d_in[5];
  const int*   dst   = (const int*)d_in[6];

  float* out = (float*)d_out;
  int*   wsI = (int*)d_ws;

  int*   sorted_src = wsI;                        // [0, 1,000,000)
  int*   hist       = wsI;                        // overlays sorted_src front
  float* colsum     = (float*)(wsI + 1000000);    // 64
  float* regA       = colsum + 64;                // 1
  float* regB       = regA + 1;                   // 64
  int*   doneG      = (int*)(regB + 64);          // 1
  int*   blockSums  = doneG + 1;                  // 782
  int*   cursor     = blockSums + SCAN_NB;        // 800,000

  // zero: hist (800k) and colsum/regA/regB/doneG (130)
  hipMemsetAsync(hist, 0, (size_t)NKEYS * sizeof(int), stream);
  hipMemsetAsync(colsum, 0, (size_t)(64 + 1 + 64 + 1) * sizeof(int), stream);

  hist_reg_kernel<<<HIST_BLOCKS + REG_BLOCKS, 256, 0, stream>>>(
      (const int4*)src, (const int4*)dst, x, u_sum, hist, regA, regB);
  scan_local  <<<SCAN_NB, 1024, 0, stream>>>(hist, cursor, blockSums);
  scan_addoff <<<SCAN_NB, 1024, 0, stream>>>(cursor, blockSums);
  reorder_kernel<<<(N_EDGES / 4 + 255) / 256, 256, 0, stream>>>(
      (const int4*)src, (const int4*)dst, cursor, sorted_src);
  gather_h    <<<GATHER_GRID, 256, 0, stream>>>(
      x, Ww, Wb, cursor, sorted_src, out, colsum, regA, regB, doneG,
      out + (size_t)N_DSTC * NCLS);
}